// Round 1
// baseline (322.953 us; speedup 1.0000x reference)
//
#include <hip/hip_runtime.h>
#include <float.h>

#define EMBED   64
#define CODES   4096
#define NROWS   65536      // 512*8192/64
#define NELEM   4194304    // 512*8192
#define BR      128        // rows per block (2 row-groups x 64 rows)
#define NSTEP   32         // steps; each step stages 64 codes per code-half
#define NTILE   128        // 32-code tiles total

typedef __attribute__((ext_vector_type(8)))  short bf16x8;   // 8 bf16 in 4 VGPRs
typedef __attribute__((ext_vector_type(16))) float f32x16;   // MFMA 32x32 accumulator

__device__ inline unsigned short f2bf(float f) {             // RNE float->bf16
    unsigned u = __float_as_uint(f);
    u += 0x7fff + ((u >> 16) & 1);
    return (unsigned short)(u >> 16);
}
__device__ inline float bf2f(unsigned short h) {
    return __uint_as_float(((unsigned)h) << 16);
}

// ws layout: [0,16K) cbuf; [16K] double accum; [32K,32K+1M) packed B-frags; +1M ET
// Fused setup: blocks 0..15 cbuf(+accum), 16..143 pack, 144..399 ET.
__global__ void vq_setup(const float* __restrict__ E, float* __restrict__ cbuf,
                         double* __restrict__ accum, bf16x8* __restrict__ packed,
                         float* __restrict__ ET) {
    const int b = blockIdx.x, t = threadIdx.x;
    if (b < 16) {
        // cbuf: emulate np.sum(E*E, axis=0) (C-order: sequential i, mul/add rounded)
        int j = b * 256 + t;
        float v = E[j];
        float s = __fmul_rn(v, v);
        for (int i = 1; i < EMBED; ++i) {
            v = E[(size_t)i * CODES + j];
            s = __fadd_rn(s, __fmul_rn(v, v));
        }
        cbuf[j] = s;
        if (j == 0) *accum = 0.0;           // d_ws poisoned 0xAA before every launch
    } else if (b < 144) {
        // pack E into MFMA B-fragment order (both splits per thread)
        int id = (b - 16) * 256 + t;        // [0, 32768)
        int lam = id & 63, kk = (id >> 6) & 3, g = id >> 8;
        int n  = g * 32 + (lam & 31);
        int kb = kk * 16 + (lam >> 5) * 8;
        bf16x8 vh, vl;
#pragma unroll
        for (int j = 0; j < 8; ++j) {
            float e = E[(size_t)(kb + j) * CODES + n];
            unsigned short hi = f2bf(e);
            vh[j] = (short)hi;
            vl[j] = (short)f2bf(e - bf2f(hi));
        }
        packed[((g * 4 + kk) * 2 + 0) * 64 + lam] = vh;
        packed[((g * 4 + kk) * 2 + 1) * 64 + lam] = vl;
    } else {
        // ET = E^T (fp32) for the coalesced output gather / exact fallback
        int id = (b - 144) * 256 + t;       // [0, 65536)
        int j = id >> 4, i0 = (id & 15) * 4;
        float4 v;
        v.x = E[(size_t)(i0 + 0) * CODES + j];
        v.y = E[(size_t)(i0 + 1) * CODES + j];
        v.z = E[(size_t)(i0 + 2) * CODES + j];
        v.w = E[(size_t)(i0 + 3) * CODES + j];
        *(float4*)(ET + (size_t)j * EMBED + i0) = v;
    }
}

// epi: 3 VALU per element; rt must be a literal (keeps M1/M2 in registers)
#define EPI(a, g, rt) do {                                                     \
    unsigned gu_ = (unsigned)(g);                                              \
_Pragma("unroll")                                                              \
    for (int e = 0; e < 16; ++e) {                                             \
        float ap_ = __uint_as_float((__float_as_uint((a)[e]) & 0xFFFFFF80u) | gu_); \
        float m1o_ = M1[rt][e];                                                \
        M1[rt][e] = fmaxf(m1o_, ap_);                                          \
        M2[rt][e] = __builtin_amdgcn_fmed3f(m1o_, M2[rt][e], ap_);             \
    } } while (0)

template <bool PRE>
__global__ __launch_bounds__(256, 2)
void vq_main(const float* __restrict__ X, const float* __restrict__ E,
             const float* __restrict__ cbuf, const bf16x8* __restrict__ packed,
             const float* __restrict__ ET, double* __restrict__ accum,
             float* __restrict__ out) {
    // [buf][half*1024 + tile*512 + kk*128 + split*64 + lane] ; 64 KB total
    __shared__ bf16x8 lbuf[2][2048];

    const int t  = threadIdx.x;
    const int l  = t & 63, wv = t >> 6;
    const int m  = l & 31, h  = l >> 5;
    const int rg = wv >> 1, ch = wv & 1;    // row-group, code-half
    const int row0 = blockIdx.x * BR;

    // ---- A fragments (persistent): 2 row-tiles (64 rows) per wave ----
    bf16x8 ah[2][4], al[2][4];
    float sqv[2];
#pragma unroll
    for (int rt = 0; rt < 2; ++rt) {
        const float* xrow = X + (size_t)(row0 + rg * 64 + rt * 32 + m) * EMBED;
        float sq = 0.f;
#pragma unroll
        for (int kk = 0; kk < 4; ++kk) {
            int kb = kk * 16 + h * 8;
            float4 v0 = *(const float4*)(xrow + kb);
            float4 v1 = *(const float4*)(xrow + kb + 4);
            float xv[8] = {v0.x, v0.y, v0.z, v0.w, v1.x, v1.y, v1.z, v1.w};
#pragma unroll
            for (int j = 0; j < 8; ++j) {
                sq = fmaf(xv[j], xv[j], sq);
                unsigned short hi = f2bf(xv[j]);
                float r = xv[j] - bf2f(hi);
                ah[rt][kk][j] = (short)hi;
                al[rt][kk][j] = (short)f2bf(r);
            }
        }
        sq += __shfl_xor(sq, 32, 64);       // lanes l and l+32 hold same row
        sqv[rt] = sq;
    }

    // top-2 of a = x.e - c/2 (max); tile index packed into low 7 mantissa bits
    float M1[2][16], M2[2][16];
#pragma unroll
    for (int rt = 0; rt < 2; ++rt)
#pragma unroll
        for (int e = 0; e < 16; ++e) { M1[rt][e] = -FLT_MAX; M2[rt][e] = -FLT_MAX; }

    if constexpr (PRE) {
        auto stage = [&](int s, int buf) {       // async global->LDS, 2 half-chunks
#pragma unroll
            for (int q = 0; q < 8; ++q) {
                int id = q * 256 + t;            // [0, 2048)
                int hh = id >> 10, w = id & 1023;
                int g  = hh * 64 + s * 2 + (w >> 9);
                const bf16x8* gp = packed + (size_t)g * 512 + (w & 511);
                bf16x8* lp = &lbuf[buf][q * 256 + wv * 64];  // wave-uniform base
                __builtin_amdgcn_global_load_lds(
                    (const __attribute__((address_space(1))) void*)gp,
                    (__attribute__((address_space(3))) void*)lp, 16, 0, 0);
            }
        };

        const int s0 = blockIdx.x & (NSTEP - 1); // rotate step order across blocks
        stage(s0, 0);
        __syncthreads();

        int b = 0;
#pragma unroll 1
        for (int ss = 0; ss < NSTEP; ++ss) {
            int s = s0 + ss; if (s >= NSTEP) s -= NSTEP;
            if (ss + 1 < NSTEP) { int sn = s + 1; if (sn >= NSTEP) sn -= NSTEP; stage(sn, b ^ 1); }
            const bf16x8* lb = &lbuf[b][ch * 1024];
            const int g0 = ch * 64 + s * 2;
            // hoist cbuf loads off the MFMA critical path (L2 latency hides
            // under the LDS reads below)
            float nc0 = -0.5f * cbuf[g0 * 32 + m];
            float nc1 = -0.5f * cbuf[g0 * 32 + 32 + m];

            bf16x8 B0[8], B1[8];
#pragma unroll
            for (int kk = 0; kk < 4; ++kk) {
                B0[kk * 2]     = lb[kk * 128 + l];
                B0[kk * 2 + 1] = lb[kk * 128 + 64 + l];
                B1[kk * 2]     = lb[512 + kk * 128 + l];
                B1[kk * 2 + 1] = lb[512 + kk * 128 + 64 + l];
            }

            // ---- tile 0: 2 row-accs, 24 MFMAs on 8 KB of B ----
            f32x16 a0, a1;
#pragma unroll
            for (int e = 0; e < 16; ++e) { a0[e] = nc0; a1[e] = nc0; }
            __builtin_amdgcn_s_setprio(1);
#pragma unroll
            for (int kk = 0; kk < 4; ++kk) {
                a0 = __builtin_amdgcn_mfma_f32_32x32x16_bf16(ah[0][kk], B0[kk * 2],     a0, 0, 0, 0);
                a1 = __builtin_amdgcn_mfma_f32_32x32x16_bf16(ah[1][kk], B0[kk * 2],     a1, 0, 0, 0);
                a0 = __builtin_amdgcn_mfma_f32_32x32x16_bf16(ah[0][kk], B0[kk * 2 + 1], a0, 0, 0, 0);
                a1 = __builtin_amdgcn_mfma_f32_32x32x16_bf16(ah[1][kk], B0[kk * 2 + 1], a1, 0, 0, 0);
                a0 = __builtin_amdgcn_mfma_f32_32x32x16_bf16(al[0][kk], B0[kk * 2],     a0, 0, 0, 0);
                a1 = __builtin_amdgcn_mfma_f32_32x32x16_bf16(al[1][kk], B0[kk * 2],     a1, 0, 0, 0);
            }
            __builtin_amdgcn_s_setprio(0);
            EPI(a0, g0, 0);
            EPI(a1, g0, 1);

            // ---- tile 1 ----
#pragma unroll
            for (int e = 0; e < 16; ++e) { a0[e] = nc1; a1[e] = nc1; }
            __builtin_amdgcn_s_setprio(1);
#pragma unroll
            for (int kk = 0; kk < 4; ++kk) {
                a0 = __builtin_amdgcn_mfma_f32_32x32x16_bf16(ah[0][kk], B1[kk * 2],     a0, 0, 0, 0);
                a1 = __builtin_amdgcn_mfma_f32_32x32x16_bf16(ah[1][kk], B1[kk * 2],     a1, 0, 0, 0);
                a0 = __builtin_amdgcn_mfma_f32_32x32x16_bf16(ah[0][kk], B1[kk * 2 + 1], a0, 0, 0, 0);
                a1 = __builtin_amdgcn_mfma_f32_32x32x16_bf16(ah[1][kk], B1[kk * 2 + 1], a1, 0, 0, 0);
                a0 = __builtin_amdgcn_mfma_f32_32x32x16_bf16(al[0][kk], B1[kk * 2],     a0, 0, 0, 0);
                a1 = __builtin_amdgcn_mfma_f32_32x32x16_bf16(al[1][kk], B1[kk * 2],     a1, 0, 0, 0);
            }
            __builtin_amdgcn_s_setprio(0);
            EPI(a0, g0 + 1, 0);
            EPI(a1, g0 + 1, 1);

            __syncthreads();
            b ^= 1;
        }
    } else {
        // fallback path (no workspace): convert E on the fly per tile
#pragma unroll 1
        for (int gg = ch * 64; gg < ch * 64 + 64; ++gg) {
            bf16x8 B[8];
            int n = gg * 32 + m;
#pragma unroll
            for (int kk = 0; kk < 4; ++kk) {
                const float* ec = E + (size_t)(kk * 16 + h * 8) * CODES + n;
                bf16x8 vh, vl;
#pragma unroll
                for (int j = 0; j < 8; ++j) {
                    float e = ec[(size_t)j * CODES];
                    unsigned short hi = f2bf(e);
                    vh[j] = (short)hi;
                    vl[j] = (short)f2bf(e - bf2f(hi));
                }
                B[kk * 2] = vh; B[kk * 2 + 1] = vl;
            }
            float nc = -0.5f * cbuf[gg * 32 + m];
            f32x16 a0, a1;
#pragma unroll
            for (int e = 0; e < 16; ++e) { a0[e] = nc; a1[e] = nc; }
#pragma unroll
            for (int kk = 0; kk < 4; ++kk) {
                a0 = __builtin_amdgcn_mfma_f32_32x32x16_bf16(ah[0][kk], B[kk * 2],     a0, 0, 0, 0);
                a1 = __builtin_amdgcn_mfma_f32_32x32x16_bf16(ah[1][kk], B[kk * 2],     a1, 0, 0, 0);
                a0 = __builtin_amdgcn_mfma_f32_32x32x16_bf16(ah[0][kk], B[kk * 2 + 1], a0, 0, 0, 0);
                a1 = __builtin_amdgcn_mfma_f32_32x32x16_bf16(ah[1][kk], B[kk * 2 + 1], a1, 0, 0, 0);
                a0 = __builtin_amdgcn_mfma_f32_32x32x16_bf16(al[0][kk], B[kk * 2],     a0, 0, 0, 0);
                a1 = __builtin_amdgcn_mfma_f32_32x32x16_bf16(al[1][kk], B[kk * 2],     a1, 0, 0, 0);
            }
            EPI(a0, gg, 0);
            EPI(a1, gg, 1);
        }
        __syncthreads();
    }

    // lbuf dead -> overlay scratch
    float* candM1 = (float*)&lbuf[0][0];      // [2][128]
    float* candM2 = candM1 + 256;             // [2][128]
    int*   candI  = (int*)(candM2 + 256);     // [2][128]
    float* rowm1  = (float*)(candI + 256);    // [128]
    float* rowsq  = rowm1 + BR;               // [128]
    int*   rowidx = (int*)(rowsq + BR);       // [128]
    int*   rowflg = rowidx + BR;              // [128]
    float* fredv  = (float*)(rowflg + BR);    // [256]
    int*   fredi  = (int*)(fredv + 256);      // [256]

    // extract indices from packed scores, then cross-lane top-2 merge
    int I1[2][16];
#pragma unroll
    for (int rt = 0; rt < 2; ++rt)
#pragma unroll
        for (int e = 0; e < 16; ++e)
            I1[rt][e] = (int)(((__float_as_uint(M1[rt][e]) & 0x7Fu) << 5) | (unsigned)m);
#pragma unroll
    for (int d = 1; d < 32; d <<= 1) {
#pragma unroll
        for (int rt = 0; rt < 2; ++rt)
#pragma unroll
            for (int e = 0; e < 16; ++e) {
                float oM1 = __shfl_xor(M1[rt][e], d, 64);
                float oM2 = __shfl_xor(M2[rt][e], d, 64);
                int   oI  = __shfl_xor(I1[rt][e], d, 64);
                float lo  = fminf(M1[rt][e], oM1);
                M2[rt][e] = fmaxf(lo, fmaxf(M2[rt][e], oM2));
                bool c = oM1 > M1[rt][e];
                I1[rt][e] = c ? oI : I1[rt][e];
                M1[rt][e] = c ? oM1 : M1[rt][e];
            }
    }
    // C/D row = (reg&3) + 8*(reg>>2) + 4*(lane>>5); one lane writes each row
#pragma unroll
    for (int rt = 0; rt < 2; ++rt)
#pragma unroll
        for (int e = 0; e < 16; ++e) {
            int r = (e & 3) + 8 * (e >> 2) + 4 * h;
            if (m == r) {
                int row = rg * 64 + rt * 32 + r;
                candM1[ch * 128 + row] = M1[rt][e];
                candM2[ch * 128 + row] = M2[rt][e];
                candI [ch * 128 + row] = I1[rt][e];
            }
        }
    if (ch == 0 && h == 0) {
        rowsq[rg * 64 + m]      = sqv[0];
        rowsq[rg * 64 + 32 + m] = sqv[1];
    }
    __syncthreads();

    // cross-code-half merge (packed values; near-ties are flagged anyway)
    if (t < BR) {
        float ca = candM1[t],       cb = candM1[128 + t];
        float a2 = candM2[t],       b2 = candM2[128 + t];
        bool take = cb > ca;
        float mm1 = take ? cb : ca;
        int   ii  = take ? candI[128 + t] : candI[t];
        float mm2 = fmaxf(fminf(ca, cb), fmaxf(a2, b2));
        rowm1[t]  = __uint_as_float(__float_as_uint(mm1) & 0xFFFFFF80u);
        rowidx[t] = ii;
        rowflg[t] = (2.f * (mm1 - mm2) < 2e-4f) ? 1 : 0;
    }
    __syncthreads();

    // ---- rare fallback: bit-exact fp32 numpy-reference emulation (uniform branch) ----
#pragma unroll 1
    for (int r = 0; r < BR; ++r) {
        if (rowflg[r] == 0) continue;
        const float* xr = X + (size_t)(row0 + r) * EMBED;
        float racc[8];
#pragma unroll
        for (int jq = 0; jq < 8; ++jq) racc[jq] = __fmul_rn(xr[jq], xr[jq]);
#pragma unroll
        for (int i = 8; i < 64; i += 8)
#pragma unroll
            for (int jq = 0; jq < 8; ++jq)
                racc[jq] = __fadd_rn(racc[jq], __fmul_rn(xr[i + jq], xr[i + jq]));
        float A = __fadd_rn(
            __fadd_rn(__fadd_rn(racc[0], racc[1]), __fadd_rn(racc[2], racc[3])),
            __fadd_rn(__fadd_rn(racc[4], racc[5]), __fadd_rn(racc[6], racc[7])));

        float best = FLT_MAX; int bestj = CODES;
#pragma unroll 1
        for (int jj = 0; jj < 16; ++jj) {
            int j = jj * 256 + t;
            float mm = 0.f;
            if constexpr (PRE) {
                const float* er = ET + (size_t)j * EMBED;   // contiguous, same bits as E column
#pragma unroll
                for (int i = 0; i < 64; ++i)
                    mm = fmaf(xr[i], er[i], mm);            // sequential FMA (BLAS k-loop)
            } else {
#pragma unroll
                for (int i = 0; i < 64; ++i)
                    mm = fmaf(xr[i], E[(size_t)i * CODES + j], mm);
            }
            float d = __fadd_rn(__fsub_rn(A, __fmul_rn(2.f, mm)), cbuf[j]);
            if (d < best || (d == best && j < bestj)) { best = d; bestj = j; }
        }
        fredv[t] = best; fredi[t] = bestj;
        __syncthreads();
        if (t == 0) {
            float B = fredv[0]; int BI = fredi[0];
            for (int c2 = 1; c2 < 256; ++c2) {
                float dc = fredv[c2]; int jc = fredi[c2];
                if (dc < B || (dc == B && jc < BI)) { B = dc; BI = jc; }
            }
            rowidx[r] = BI;
        }
        __syncthreads();
    }

    // ---- outputs ----
    if (t < BR) out[(size_t)NELEM + 1 + row0 + t] = (float)rowidx[t];  // idx as float
    if (t == 0) {
        float bs = 0.f;
        for (int r = 0; r < BR; ++r) bs += rowsq[r] - 2.f * rowm1[r];  // sum (x-e)^2
        atomicAdd(accum, (double)bs);
    }
    {
        int r = t >> 1, i0 = (t & 1) * 32;
        int j = rowidx[r];
        float* dst = out + (size_t)(row0 + r) * EMBED + i0;
        if constexpr (PRE) {
            const float* src = ET + (size_t)j * EMBED + i0;
#pragma unroll
            for (int g = 0; g < 8; ++g)
                *(float4*)(dst + g * 4) = *(const float4*)(src + g * 4);
        } else {
#pragma unroll
            for (int g = 0; g < 8; ++g) {
                float4 v;
                v.x = E[(size_t)(i0 + g * 4 + 0) * CODES + j];
                v.y = E[(size_t)(i0 + g * 4 + 1) * CODES + j];
                v.z = E[(size_t)(i0 + g * 4 + 2) * CODES + j];
                v.w = E[(size_t)(i0 + g * 4 + 3) * CODES + j];
                *(float4*)(dst + g * 4) = v;
            }
        }
    }
}

__global__ void vq_finalize(const double* __restrict__ accum, float* __restrict__ out) {
    out[NELEM] = (float)(0.25 * (*accum) / (double)NELEM);
}

extern "C" void kernel_launch(void* const* d_in, const int* in_sizes, int n_in,
                              void* d_out, int out_size, void* d_ws, size_t ws_size,
                              hipStream_t stream) {
    const float* X = (const float*)d_in[0];   // (512, 8192, 1) f32 -> 65536 rows x 64
    const float* E = (const float*)d_in[1];   // (64, 4096) f32 row-major
    float* out = (float*)d_out;
    float*  cbuf   = (float*)d_ws;
    double* accum  = (double*)((char*)d_ws + 16384);
    bf16x8* packed = (bf16x8*)((char*)d_ws + 32768);
    float*  ET     = (float*)((char*)d_ws + 32768 + 1048576);
    const size_t need = 32768 + 1048576 + 1048576;
    const bool pre = (ws_size >= need);       // constant across calls -> same work every call

    vq_setup<<<pre ? 400 : 16, 256, 0, stream>>>(E, cbuf, accum, packed, ET);
    if (pre)
        vq_main<true><<<NROWS / BR, 256, 0, stream>>>(X, E, cbuf, packed, ET, accum, out);
    else
        vq_main<false><<<NROWS / BR, 256, 0, stream>>>(X, E, cbuf, packed, ET, accum, out);
    vq_finalize<<<1, 1, 0, stream>>>(accum, out);
}

// Round 2
// 320.746 us; speedup vs baseline: 1.0069x; 1.0069x over previous
//
#include <hip/hip_runtime.h>
#include <float.h>

#define EMBED   64
#define CODES   4096
#define NROWS   65536      // 512*8192/64
#define NELEM   4194304    // 512*8192
#define BR      128        // rows per block (2 row-groups x 64 rows)
#define NSTEP   32         // steps; each step stages 64 codes per code-half
#define NTILE   128        // 32-code tiles total

typedef __attribute__((ext_vector_type(8)))  short bf16x8;   // 8 bf16 in 4 VGPRs
typedef __attribute__((ext_vector_type(16))) float f32x16;   // MFMA 32x32 accumulator

__device__ inline unsigned short f2bf(float f) {             // RNE float->bf16
    unsigned u = __float_as_uint(f);
    u += 0x7fff + ((u >> 16) & 1);
    return (unsigned short)(u >> 16);
}
__device__ inline float bf2f(unsigned short h) {
    return __uint_as_float(((unsigned)h) << 16);
}

// ws layout: [0,16K) cbuf; [16K] double accum; [32K,32K+1M) packed B-frags; +1M ET
// Fused setup: blocks 0..15 cbuf(+accum), 16..143 pack, 144..399 ET.
__global__ void vq_setup(const float* __restrict__ E, float* __restrict__ cbuf,
                         double* __restrict__ accum, bf16x8* __restrict__ packed,
                         float* __restrict__ ET) {
    const int b = blockIdx.x, t = threadIdx.x;
    if (b < 16) {
        // cbuf: emulate np.sum(E*E, axis=0) (C-order: sequential i, mul/add rounded)
        int j = b * 256 + t;
        float v = E[j];
        float s = __fmul_rn(v, v);
        for (int i = 1; i < EMBED; ++i) {
            v = E[(size_t)i * CODES + j];
            s = __fadd_rn(s, __fmul_rn(v, v));
        }
        cbuf[j] = s;
        if (j == 0) *accum = 0.0;           // d_ws poisoned 0xAA before every launch
    } else if (b < 144) {
        // pack E into MFMA B-fragment order (both splits per thread)
        int id = (b - 16) * 256 + t;        // [0, 32768)
        int lam = id & 63, kk = (id >> 6) & 3, g = id >> 8;
        int n  = g * 32 + (lam & 31);
        int kb = kk * 16 + (lam >> 5) * 8;
        bf16x8 vh, vl;
#pragma unroll
        for (int j = 0; j < 8; ++j) {
            float e = E[(size_t)(kb + j) * CODES + n];
            unsigned short hi = f2bf(e);
            vh[j] = (short)hi;
            vl[j] = (short)f2bf(e - bf2f(hi));
        }
        packed[((g * 4 + kk) * 2 + 0) * 64 + lam] = vh;
        packed[((g * 4 + kk) * 2 + 1) * 64 + lam] = vl;
    } else {
        // ET = E^T (fp32) for the coalesced output gather / exact fallback
        int id = (b - 144) * 256 + t;       // [0, 65536)
        int j = id >> 4, i0 = (id & 15) * 4;
        float4 v;
        v.x = E[(size_t)(i0 + 0) * CODES + j];
        v.y = E[(size_t)(i0 + 1) * CODES + j];
        v.z = E[(size_t)(i0 + 2) * CODES + j];
        v.w = E[(size_t)(i0 + 3) * CODES + j];
        *(float4*)(ET + (size_t)j * EMBED + i0) = v;
    }
}

// epi: 3 VALU per element; rt must be a literal (keeps M1/M2 in registers)
#define EPI(a, g, rt) do {                                                     \
    unsigned gu_ = (unsigned)(g);                                              \
_Pragma("unroll")                                                              \
    for (int e = 0; e < 16; ++e) {                                             \
        float ap_ = __uint_as_float((__float_as_uint((a)[e]) & 0xFFFFFF80u) | gu_); \
        float m1o_ = M1[rt][e];                                                \
        M1[rt][e] = fmaxf(m1o_, ap_);                                          \
        M2[rt][e] = __builtin_amdgcn_fmed3f(m1o_, M2[rt][e], ap_);             \
    } } while (0)

template <bool PRE>
__global__ __launch_bounds__(256, 2)
void vq_main(const float* __restrict__ X, const float* __restrict__ E,
             const float* __restrict__ cbuf, const bf16x8* __restrict__ packed,
             const float* __restrict__ ET, double* __restrict__ accum,
             float* __restrict__ out) {
    // [buf][half*1024 + tile*512 + kk*128 + split*64 + lane] ; 64 KB total
    __shared__ bf16x8 lbuf[2][2048];

    const int t  = threadIdx.x;
    const int l  = t & 63, wv = t >> 6;
    const int m  = l & 31, h  = l >> 5;
    const int rg = wv >> 1, ch = wv & 1;    // row-group, code-half
    const int row0 = blockIdx.x * BR;

    // ---- A fragments (persistent): 2 row-tiles (64 rows) per wave ----
    bf16x8 ah[2][4], al[2][4];
    float sqv[2];
#pragma unroll
    for (int rt = 0; rt < 2; ++rt) {
        const float* xrow = X + (size_t)(row0 + rg * 64 + rt * 32 + m) * EMBED;
        float sq = 0.f;
#pragma unroll
        for (int kk = 0; kk < 4; ++kk) {
            int kb = kk * 16 + h * 8;
            float4 v0 = *(const float4*)(xrow + kb);
            float4 v1 = *(const float4*)(xrow + kb + 4);
            float xv[8] = {v0.x, v0.y, v0.z, v0.w, v1.x, v1.y, v1.z, v1.w};
#pragma unroll
            for (int j = 0; j < 8; ++j) {
                sq = fmaf(xv[j], xv[j], sq);
                unsigned short hi = f2bf(xv[j]);
                float r = xv[j] - bf2f(hi);
                ah[rt][kk][j] = (short)hi;
                al[rt][kk][j] = (short)f2bf(r);
            }
        }
        sq += __shfl_xor(sq, 32, 64);       // lanes l and l+32 hold same row
        sqv[rt] = sq;
    }

    // top-2 of a = x.e - c/2 (max); tile index packed into low 7 mantissa bits
    float M1[2][16], M2[2][16];
#pragma unroll
    for (int rt = 0; rt < 2; ++rt)
#pragma unroll
        for (int e = 0; e < 16; ++e) { M1[rt][e] = -FLT_MAX; M2[rt][e] = -FLT_MAX; }

    if constexpr (PRE) {
        auto stage = [&](int s, int buf) {       // async global->LDS, 2 half-chunks
#pragma unroll
            for (int q = 0; q < 8; ++q) {
                int id = q * 256 + t;            // [0, 2048)
                int hh = id >> 10, w = id & 1023;
                int g  = hh * 64 + s * 2 + (w >> 9);
                const bf16x8* gp = packed + (size_t)g * 512 + (w & 511);
                bf16x8* lp = &lbuf[buf][q * 256 + wv * 64];  // wave-uniform base
                __builtin_amdgcn_global_load_lds(
                    (const __attribute__((address_space(1))) void*)gp,
                    (__attribute__((address_space(3))) void*)lp, 16, 0, 0);
            }
        };

        const int s0 = blockIdx.x & (NSTEP - 1); // rotate step order across blocks
        stage(s0, 0);

        // software pipeline: prev-tile accumulators, epilogue delayed by one tile
        f32x16 pA, pB; int pg = 0;
#pragma unroll
        for (int e = 0; e < 16; ++e) { pA[e] = -FLT_MAX; pB[e] = -FLT_MAX; }  // harmless dummy

        __syncthreads();

        int b = 0;
#pragma unroll 1
        for (int ss = 0; ss < NSTEP; ++ss) {
            int s = s0 + ss; if (s >= NSTEP) s -= NSTEP;
            if (ss + 1 < NSTEP) { int sn = s + 1; if (sn >= NSTEP) sn -= NSTEP; stage(sn, b ^ 1); }
            const bf16x8* lb = &lbuf[b][ch * 1024];
            const int g0 = ch * 64 + s * 2;
            // hoist cbuf loads off the MFMA critical path
            float nc0 = -0.5f * cbuf[g0 * 32 + m];
            float nc1 = -0.5f * cbuf[g0 * 32 + 32 + m];

#pragma unroll
            for (int tl = 0; tl < 2; ++tl) {
                // issue LDS reads for this tile
                bf16x8 B[8];
#pragma unroll
                for (int kk = 0; kk < 4; ++kk) {
                    B[kk * 2]     = lb[tl * 512 + kk * 128 + l];
                    B[kk * 2 + 1] = lb[tl * 512 + kk * 128 + 64 + l];
                }
                float nc = tl ? nc1 : nc0;
                // delayed epilogue of previous tile: independent VALU, fills
                // the lgkm shadow and co-issues with MFMA
                EPI(pA, pg, 0);
                EPI(pB, pg, 1);
                f32x16 a0, a1;
#pragma unroll
                for (int e = 0; e < 16; ++e) { a0[e] = nc; a1[e] = nc; }
                __builtin_amdgcn_s_setprio(1);
#pragma unroll
                for (int kk = 0; kk < 4; ++kk) {  // two interleaved chains, gap 2
                    a0 = __builtin_amdgcn_mfma_f32_32x32x16_bf16(ah[0][kk], B[kk * 2],     a0, 0, 0, 0);
                    a1 = __builtin_amdgcn_mfma_f32_32x32x16_bf16(ah[1][kk], B[kk * 2],     a1, 0, 0, 0);
                    a0 = __builtin_amdgcn_mfma_f32_32x32x16_bf16(ah[0][kk], B[kk * 2 + 1], a0, 0, 0, 0);
                    a1 = __builtin_amdgcn_mfma_f32_32x32x16_bf16(ah[1][kk], B[kk * 2 + 1], a1, 0, 0, 0);
                    a0 = __builtin_amdgcn_mfma_f32_32x32x16_bf16(al[0][kk], B[kk * 2],     a0, 0, 0, 0);
                    a1 = __builtin_amdgcn_mfma_f32_32x32x16_bf16(al[1][kk], B[kk * 2],     a1, 0, 0, 0);
                }
                __builtin_amdgcn_s_setprio(0);
                pA = a0; pB = a1; pg = g0 + tl;
            }
            __syncthreads();
            b ^= 1;
        }
        EPI(pA, pg, 0);
        EPI(pB, pg, 1);
    } else {
        // fallback path (no workspace): convert E on the fly per tile
#pragma unroll 1
        for (int gg = ch * 64; gg < ch * 64 + 64; ++gg) {
            bf16x8 B[8];
            int n = gg * 32 + m;
#pragma unroll
            for (int kk = 0; kk < 4; ++kk) {
                const float* ec = E + (size_t)(kk * 16 + h * 8) * CODES + n;
                bf16x8 vh, vl;
#pragma unroll
                for (int j = 0; j < 8; ++j) {
                    float e = ec[(size_t)j * CODES];
                    unsigned short hi = f2bf(e);
                    vh[j] = (short)hi;
                    vl[j] = (short)f2bf(e - bf2f(hi));
                }
                B[kk * 2] = vh; B[kk * 2 + 1] = vl;
            }
            float nc = -0.5f * cbuf[gg * 32 + m];
            f32x16 a0, a1;
#pragma unroll
            for (int e = 0; e < 16; ++e) { a0[e] = nc; a1[e] = nc; }
#pragma unroll
            for (int kk = 0; kk < 4; ++kk) {
                a0 = __builtin_amdgcn_mfma_f32_32x32x16_bf16(ah[0][kk], B[kk * 2],     a0, 0, 0, 0);
                a1 = __builtin_amdgcn_mfma_f32_32x32x16_bf16(ah[1][kk], B[kk * 2],     a1, 0, 0, 0);
                a0 = __builtin_amdgcn_mfma_f32_32x32x16_bf16(ah[0][kk], B[kk * 2 + 1], a0, 0, 0, 0);
                a1 = __builtin_amdgcn_mfma_f32_32x32x16_bf16(ah[1][kk], B[kk * 2 + 1], a1, 0, 0, 0);
                a0 = __builtin_amdgcn_mfma_f32_32x32x16_bf16(al[0][kk], B[kk * 2],     a0, 0, 0, 0);
                a1 = __builtin_amdgcn_mfma_f32_32x32x16_bf16(al[1][kk], B[kk * 2],     a1, 0, 0, 0);
            }
            EPI(a0, gg, 0);
            EPI(a1, gg, 1);
        }
        __syncthreads();
    }

    // lbuf dead -> overlay scratch
    float* candM1 = (float*)&lbuf[0][0];      // [2][128]
    float* candM2 = candM1 + 256;             // [2][128]
    int*   candI  = (int*)(candM2 + 256);     // [2][128]
    float* rowm1  = (float*)(candI + 256);    // [128]
    float* rowsq  = rowm1 + BR;               // [128]
    int*   rowidx = (int*)(rowsq + BR);       // [128]
    int*   rowflg = rowidx + BR;              // [128]
    float* fredv  = (float*)(rowflg + BR);    // [256]
    int*   fredi  = (int*)(fredv + 256);      // [256]

    // extract indices from packed scores, then cross-lane top-2 merge
    int I1[2][16];
#pragma unroll
    for (int rt = 0; rt < 2; ++rt)
#pragma unroll
        for (int e = 0; e < 16; ++e)
            I1[rt][e] = (int)(((__float_as_uint(M1[rt][e]) & 0x7Fu) << 5) | (unsigned)m);
#pragma unroll
    for (int d = 1; d < 32; d <<= 1) {
#pragma unroll
        for (int rt = 0; rt < 2; ++rt)
#pragma unroll
            for (int e = 0; e < 16; ++e) {
                float oM1 = __shfl_xor(M1[rt][e], d, 64);
                float oM2 = __shfl_xor(M2[rt][e], d, 64);
                int   oI  = __shfl_xor(I1[rt][e], d, 64);
                float lo  = fminf(M1[rt][e], oM1);
                M2[rt][e] = fmaxf(lo, fmaxf(M2[rt][e], oM2));
                bool c = oM1 > M1[rt][e];
                I1[rt][e] = c ? oI : I1[rt][e];
                M1[rt][e] = c ? oM1 : M1[rt][e];
            }
    }
    // C/D row = (reg&3) + 8*(reg>>2) + 4*(lane>>5); one lane writes each row
#pragma unroll
    for (int rt = 0; rt < 2; ++rt)
#pragma unroll
        for (int e = 0; e < 16; ++e) {
            int r = (e & 3) + 8 * (e >> 2) + 4 * h;
            if (m == r) {
                int row = rg * 64 + rt * 32 + r;
                candM1[ch * 128 + row] = M1[rt][e];
                candM2[ch * 128 + row] = M2[rt][e];
                candI [ch * 128 + row] = I1[rt][e];
            }
        }
    if (ch == 0 && h == 0) {
        rowsq[rg * 64 + m]      = sqv[0];
        rowsq[rg * 64 + 32 + m] = sqv[1];
    }
    __syncthreads();

    // cross-code-half merge (packed values; near-ties are flagged anyway)
    if (t < BR) {
        float ca = candM1[t],       cb = candM1[128 + t];
        float a2 = candM2[t],       b2 = candM2[128 + t];
        bool take = cb > ca;
        float mm1 = take ? cb : ca;
        int   ii  = take ? candI[128 + t] : candI[t];
        float mm2 = fmaxf(fminf(ca, cb), fmaxf(a2, b2));
        rowm1[t]  = __uint_as_float(__float_as_uint(mm1) & 0xFFFFFF80u);
        rowidx[t] = ii;
        rowflg[t] = (2.f * (mm1 - mm2) < 2e-4f) ? 1 : 0;
    }
    __syncthreads();

    // ---- rare fallback: bit-exact fp32 numpy-reference emulation (uniform branch) ----
#pragma unroll 1
    for (int r = 0; r < BR; ++r) {
        if (rowflg[r] == 0) continue;
        const float* xr = X + (size_t)(row0 + r) * EMBED;
        float racc[8];
#pragma unroll
        for (int jq = 0; jq < 8; ++jq) racc[jq] = __fmul_rn(xr[jq], xr[jq]);
#pragma unroll
        for (int i = 8; i < 64; i += 8)
#pragma unroll
            for (int jq = 0; jq < 8; ++jq)
                racc[jq] = __fadd_rn(racc[jq], __fmul_rn(xr[i + jq], xr[i + jq]));
        float A = __fadd_rn(
            __fadd_rn(__fadd_rn(racc[0], racc[1]), __fadd_rn(racc[2], racc[3])),
            __fadd_rn(__fadd_rn(racc[4], racc[5]), __fadd_rn(racc[6], racc[7])));

        float best = FLT_MAX; int bestj = CODES;
#pragma unroll 1
        for (int jj = 0; jj < 16; ++jj) {
            int j = jj * 256 + t;
            float mm = 0.f;
            if constexpr (PRE) {
                const float* er = ET + (size_t)j * EMBED;   // contiguous, same bits as E column
#pragma unroll
                for (int i = 0; i < 64; ++i)
                    mm = fmaf(xr[i], er[i], mm);            // sequential FMA (BLAS k-loop)
            } else {
#pragma unroll
                for (int i = 0; i < 64; ++i)
                    mm = fmaf(xr[i], E[(size_t)i * CODES + j], mm);
            }
            float d = __fadd_rn(__fsub_rn(A, __fmul_rn(2.f, mm)), cbuf[j]);
            if (d < best || (d == best && j < bestj)) { best = d; bestj = j; }
        }
        fredv[t] = best; fredi[t] = bestj;
        __syncthreads();
        if (t == 0) {
            float B = fredv[0]; int BI = fredi[0];
            for (int c2 = 1; c2 < 256; ++c2) {
                float dc = fredv[c2]; int jc = fredi[c2];
                if (dc < B || (dc == B && jc < BI)) { B = dc; BI = jc; }
            }
            rowidx[r] = BI;
        }
        __syncthreads();
    }

    // ---- outputs ----
    if (t < BR) out[(size_t)NELEM + 1 + row0 + t] = (float)rowidx[t];  // idx as float
    if (t == 0) {
        float bs = 0.f;
        for (int r = 0; r < BR; ++r) bs += rowsq[r] - 2.f * rowm1[r];  // sum (x-e)^2
        atomicAdd(accum, (double)bs);
    }
    {
        int r = t >> 1, i0 = (t & 1) * 32;
        int j = rowidx[r];
        float* dst = out + (size_t)(row0 + r) * EMBED + i0;
        if constexpr (PRE) {
            const float* src = ET + (size_t)j * EMBED + i0;
#pragma unroll
            for (int g = 0; g < 8; ++g)
                *(float4*)(dst + g * 4) = *(const float4*)(src + g * 4);
        } else {
#pragma unroll
            for (int g = 0; g < 8; ++g) {
                float4 v;
                v.x = E[(size_t)(i0 + g * 4 + 0) * CODES + j];
                v.y = E[(size_t)(i0 + g * 4 + 1) * CODES + j];
                v.z = E[(size_t)(i0 + g * 4 + 2) * CODES + j];
                v.w = E[(size_t)(i0 + g * 4 + 3) * CODES + j];
                *(float4*)(dst + g * 4) = v;
            }
        }
    }
}

__global__ void vq_finalize(const double* __restrict__ accum, float* __restrict__ out) {
    out[NELEM] = (float)(0.25 * (*accum) / (double)NELEM);
}

extern "C" void kernel_launch(void* const* d_in, const int* in_sizes, int n_in,
                              void* d_out, int out_size, void* d_ws, size_t ws_size,
                              hipStream_t stream) {
    const float* X = (const float*)d_in[0];   // (512, 8192, 1) f32 -> 65536 rows x 64
    const float* E = (const float*)d_in[1];   // (64, 4096) f32 row-major
    float* out = (float*)d_out;
    float*  cbuf   = (float*)d_ws;
    double* accum  = (double*)((char*)d_ws + 16384);
    bf16x8* packed = (bf16x8*)((char*)d_ws + 32768);
    float*  ET     = (float*)((char*)d_ws + 32768 + 1048576);
    const size_t need = 32768 + 1048576 + 1048576;
    const bool pre = (ws_size >= need);       // constant across calls -> same work every call

    vq_setup<<<pre ? 400 : 16, 256, 0, stream>>>(E, cbuf, accum, packed, ET);
    if (pre)
        vq_main<true><<<NROWS / BR, 256, 0, stream>>>(X, E, cbuf, packed, ET, accum, out);
    else
        vq_main<false><<<NROWS / BR, 256, 0, stream>>>(X, E, cbuf, packed, ET, accum, out);
    vq_finalize<<<1, 1, 0, stream>>>(accum, out);
}